// Round 6
// baseline (971.600 us; speedup 1.0000x reference)
//
#include <hip/hip_runtime.h>
#include <hip/hip_bf16.h>
#include <cstdint>
#include <cstddef>

using bf16 = __hip_bfloat16;
typedef __attribute__((ext_vector_type(8))) short bf16x8;
typedef __attribute__((ext_vector_type(4))) float floatx4;

#define GLOBAL_AS __attribute__((address_space(1)))
#define LDS_AS    __attribute__((address_space(3)))

__device__ __forceinline__ void async_copy16(void* lds, const void* g) {
    __builtin_amdgcn_global_load_lds((GLOBAL_AS void*)(g), (LDS_AS void*)(lds), 16, 0, 0);
}

__device__ __forceinline__ floatx4 mfma_bf16(bf16x8 a, bf16x8 b, floatx4 c) {
    return __builtin_amdgcn_mfma_f32_16x16x32_bf16(a, b, c, 0, 0, 0);
}

// fp32 -> bf16 elementwise, 4 elements/thread. n must be a multiple of 4.
__global__ void cvt_f32_bf16(const float* __restrict__ src, bf16* __restrict__ dst, int n) {
    int i = (blockIdx.x * blockDim.x + threadIdx.x) * 4;
    if (i < n) {
        float4 v = *(const float4*)(src + i);
        __align__(8) bf16 t[4];
        t[0] = __float2bfloat16(v.x);
        t[1] = __float2bfloat16(v.y);
        t[2] = __float2bfloat16(v.z);
        t[3] = __float2bfloat16(v.w);
        *(short4*)(dst + i) = *(const short4*)t;
    }
}

// ===========================================================================
// 256x256 8-phase GEMM, v2: ds_reads software-pipelined ONE PHASE AHEAD.
// Each phase: {issue next phase's ds_reads; issue 1 half-tile stage; BAR;
// counted lgkmcnt (just-issued reads still in flight); MFMA on operands read
// LAST phase; BAR}. MFMA order per K-tile: (a0*b01)(a0*b23)(a1*b01)(a1*b23)
// so 2 A-sets + 2 B-sets suffice (96 operand VGPRs). lgkmcnt(0) BEFORE the
// stages at ph2/ph6 drains pending ds_reads of the buffer the DMA is about
// to overwrite (hazard invisible to the compiler). vmcnt(4) at ph3/ph7 only.
// Bijective XCD swizzle on the 256-block grid (32 contiguous tiles per XCD).
// ===========================================================================
#define MMBLK(AF, BF, MB, NB) do {                                             \
    __builtin_amdgcn_s_setprio(1);                                             \
    _Pragma("unroll") for (int kk = 0; kk < 2; ++kk)                           \
    _Pragma("unroll") for (int mi = 0; mi < 4; ++mi)                           \
    _Pragma("unroll") for (int ni = 0; ni < 2; ++ni)                           \
        acc[(MB) + mi][(NB) + ni] =                                            \
            mfma_bf16(AF[mi][kk], BF[ni][kk], acc[(MB) + mi][(NB) + ni]);      \
    __builtin_amdgcn_s_setprio(0);                                             \
} while (0)

#define READ_A(DST, BI, H) do {                                                \
    _Pragma("unroll") for (int mi = 0; mi < 4; ++mi) {                         \
        DST[mi][0] = LDA(BI, (H) * 4 + mi, 0);                                 \
        DST[mi][1] = LDA(BI, (H) * 4 + mi, 1);                                 \
    }                                                                          \
} while (0)

#define READ_B(DST, BI, P) do {                                                \
    _Pragma("unroll") for (int ni = 0; ni < 2; ++ni) {                         \
        DST[ni][0] = LDB(BI, (P) * 2 + ni, 0);                                 \
        DST[ni][1] = LDB(BI, (P) * 2 + ni, 1);                                 \
    }                                                                          \
} while (0)

#define BAR()    __builtin_amdgcn_s_barrier()
#define LGKM(N)  asm volatile("s_waitcnt lgkmcnt(" #N ")" ::: "memory")
#define VM4()    asm volatile("s_waitcnt vmcnt(4)" ::: "memory")
#define VM0()    asm volatile("s_waitcnt vmcnt(0)" ::: "memory")

template <int OUTF>
__global__ __launch_bounds__(512, 2) void gemm256_bt_bias(
    const bf16* __restrict__ A, const bf16* __restrict__ W,
    const float* __restrict__ bias, void* __restrict__ Cv,
    int M, int N, int K, float cscale)
{
    __shared__ __align__(16) bf16 sA[2][2][128 * 64];
    __shared__ __align__(16) bf16 sB[2][2][128 * 64];

    const int tid  = threadIdx.x;
    const int lane = tid & 63;
    const int wave = tid >> 6;       // 0..7
    const int quad = lane >> 4;
    const int l16  = lane & 15;
    const int wmi  = wave >> 2;      // 0..1: A half / output rows wmi*128
    const int wni  = wave & 3;       // 0..3: output cols wni*64; B half = wni>>1

    // bijective XCD swizzle: 256 blocks, 8 XCDs -> 32 contiguous tiles/XCD
    const int nbx  = gridDim.x;
    const int bidl = blockIdx.y * nbx + blockIdx.x;
    const int cpx  = (nbx * gridDim.y) >> 3;
    const int sid  = (bidl & 7) * cpx + (bidl >> 3);
    const int bm   = sid % nbx;
    const int bn   = sid / nbx;

    const int srow = tid >> 3;       // staging granule row (i=0)
    const int sc16 = tid & 7;

    auto STAGE = [&](bf16* dst, const bf16* G, int rowbase, int kt) {
#pragma unroll
        for (int i = 0; i < 2; ++i) {
            const int row = i * 64 + srow;
            async_copy16(dst + (i * 512 + tid) * 8,
                         G + (size_t)(rowbase + row) * K + kt * 64 + ((sc16 ^ (row & 7)) * 8));
        }
    };
    auto LDA = [&](int bi, int mi, int kk) -> bf16x8 {
        const bf16* base = &sA[bi][wmi][0];
        const int r = mi * 16 + l16;
        return *(const bf16x8*)(base + r * 64 + (((kk * 4 + quad) ^ (r & 7)) * 8));
    };
    auto LDB = [&](int bi, int ni, int kk) -> bf16x8 {
        const bf16* base = &sB[bi][wni >> 1][0];
        const int r = (wni & 1) * 64 + ni * 16 + l16;
        return *(const bf16x8*)(base + r * 64 + (((kk * 4 + quad) ^ (r & 7)) * 8));
    };

    floatx4 acc[8][4];
#pragma unroll
    for (int i = 0; i < 8; ++i)
#pragma unroll
        for (int j = 0; j < 4; ++j) acc[i][j] = (floatx4){0.f, 0.f, 0.f, 0.f};

    const int rowA = bm * 256;
    const int rowB = bn * 256;
    const int iters = K >> 7;        // 2 K-tiles (BK=64) per iteration

    // ---- prologue: buf0 <- K-tile 0 (4 half-tiles), buf1 <- A of K-tile 1
    STAGE(&sA[0][0][0], A, rowA + 0,   0);
    STAGE(&sA[0][1][0], A, rowA + 128, 0);
    STAGE(&sB[0][0][0], W, rowB + 0,   0);
    STAGE(&sB[0][1][0], W, rowB + 128, 0);
    STAGE(&sA[1][0][0], A, rowA + 0,   1);
    STAGE(&sA[1][1][0], A, rowA + 128, 1);
    VM4();                            // buf0's 8 loads landed; A(1) in flight
    BAR();

    bf16x8 a0[4][2], a1[4][2], b01[2][2], b23[2][2];
    READ_A(a0, 0, 0);                 // pre-read ph0 operands (12 reads)
    READ_B(b01, 0, 0);

    for (int i = 0; i < iters; ++i) {
        const int kt = 2 * i;
        const bool nl = (i + 1 < iters);

        // -- ph0: MFMA(a0*b01) buf0 | read b23(buf0) | stage B0(kt+1)->buf1
        READ_B(b23, 0, 1);
        STAGE(&sB[1][0][0], W, rowB + 0, kt + 1);
        BAR(); LGKM(4);
        MMBLK(a0, b01, 0, 0);
        BAR();
        // -- ph1: MFMA(a0*b23) | read a1(buf0) | stage B1(kt+1)->buf1
        READ_A(a1, 0, 1);
        STAGE(&sB[1][1][0], W, rowB + 128, kt + 1);
        BAR(); LGKM(8);
        MMBLK(a0, b23, 0, 2);
        BAR();
        // -- ph2: MFMA(a1*b01) | drain a1 reads, then stage A0(kt+2)->buf0
        LGKM(0);                      // a1 (reads of sA[0]) retired before DMA overwrite
        if (nl) STAGE(&sA[0][0][0], A, rowA + 0, kt + 2);
        BAR();
        MMBLK(a1, b01, 4, 0);
        BAR();
        // -- ph3: MFMA(a1*b23) | stage A1(kt+2) | vmcnt: buf1(kt+1) landed |
        //         read a0',b01' (buf1) for ph4
        if (nl) { STAGE(&sA[0][1][0], A, rowA + 128, kt + 2); VM4(); }
        else    { VM0(); }
        BAR();
        READ_A(a0, 1, 0);
        READ_B(b01, 1, 0);
        LGKM(12);
        MMBLK(a1, b23, 4, 2);
        BAR();
        // -- ph4: MFMA(a0'*b01') buf1 | read b23'(buf1) | stage B0(kt+2)->buf0
        READ_B(b23, 1, 1);
        if (nl) STAGE(&sB[0][0][0], W, rowB + 0, kt + 2);
        BAR(); LGKM(4);
        MMBLK(a0, b01, 0, 0);
        BAR();
        // -- ph5: MFMA(a0'*b23') | read a1'(buf1) | stage B1(kt+2)->buf0
        READ_A(a1, 1, 1);
        if (nl) STAGE(&sB[0][1][0], W, rowB + 128, kt + 2);
        BAR(); LGKM(8);
        MMBLK(a0, b23, 0, 2);
        BAR();
        // -- ph6: MFMA(a1'*b01') | drain a1' reads, then stage A0(kt+3)->buf1
        LGKM(0);
        if (nl) STAGE(&sA[1][0][0], A, rowA + 0, kt + 3);
        BAR();
        MMBLK(a1, b01, 4, 0);
        BAR();
        // -- ph7: MFMA(a1'*b23') | stage A1(kt+3) | vmcnt: buf0(kt+2) landed |
        //         read a0'',b01'' (buf0) for next iteration's ph0
        if (nl) { STAGE(&sA[1][1][0], A, rowA + 128, kt + 3); VM4(); }
        BAR();
        if (nl) {
            READ_A(a0, 0, 0);
            READ_B(b01, 0, 0);
            LGKM(12);
        }
        MMBLK(a1, b23, 4, 2);
        BAR();
    }

    // ---- epilogue
#pragma unroll
    for (int mi = 0; mi < 8; ++mi) {
        const int row0 = bm * 256 + wmi * 128 + mi * 16 + quad * 4;
#pragma unroll
        for (int ni = 0; ni < 4; ++ni) {
            const int col = bn * 256 + wni * 64 + ni * 16 + l16;
            const float bv = bias[col];
            if (OUTF) {
                float* C = (float*)Cv;
#pragma unroll
                for (int r = 0; r < 4; ++r)
                    C[(size_t)(row0 + r) * N + col] = (acc[mi][ni][r] + bv) * cscale;
            } else {
                bf16* C = (bf16*)Cv;
#pragma unroll
                for (int r = 0; r < 4; ++r)
                    C[(size_t)(row0 + r) * N + col] = __float2bfloat16((acc[mi][ni][r] + bv) * cscale);
            }
        }
    }
}

// Fused K+V projection (128^2 structure; 512 blocks keeps all CUs busy).
__global__ __launch_bounds__(256, 3) void gemm_kv(
    const bf16* __restrict__ A,
    const bf16* __restrict__ Wk, const bf16* __restrict__ Wv,
    const float* __restrict__ bk, const float* __restrict__ bv,
    bf16* __restrict__ kout, bf16* __restrict__ vt,
    int M, int K)
{
    __shared__ __align__(16) bf16 As[128 * 32];
    __shared__ __align__(16) bf16 Ws[128 * 32];

    const int tid  = threadIdx.x;
    const int lane = tid & 63;
    const int wave = tid >> 6;
    const int quad = lane >> 4;
    const int l16  = lane & 15;
    const int wm = (wave >> 1) * 64;
    const int wn = (wave & 1) * 64;

    const int bm = blockIdx.x;
    const int bn = blockIdx.y;
    const bool isK = (bn < 8);
    const int nb = isK ? bn : (bn - 8);
    const bf16* Wsel  = isK ? Wk : Wv;
    const float* bsel = isK ? bk : bv;

    floatx4 acc[4][4];
#pragma unroll
    for (int i = 0; i < 4; ++i)
#pragma unroll
        for (int j = 0; j < 4; ++j) acc[i][j] = (floatx4){0.f, 0.f, 0.f, 0.f};

    const int srow = tid >> 2;
    const int scol = (tid & 3) * 8;
    const bf16* gA = A    + (size_t)(bm * 128 + srow) * K + scol;
    const bf16* gW = Wsel + (size_t)(nb * 128 + srow) * K + scol;
    bf16* lA0 = As + tid * 8;
    bf16* lA1 = As + 2048 + tid * 8;
    bf16* lW0 = Ws + tid * 8;
    bf16* lW1 = Ws + 2048 + tid * 8;
    const size_t skip = (size_t)64 * K;

    const int kt_n = K >> 5;
    for (int kt = 0; kt < kt_n; ++kt) {
        __syncthreads();
        const bf16* ga = gA + kt * 32;
        const bf16* gw = gW + kt * 32;
        async_copy16(lA0, ga);
        async_copy16(lA1, ga + skip);
        async_copy16(lW0, gw);
        async_copy16(lW1, gw + skip);
        __syncthreads();

        bf16x8 af[4], bfr[4];
#pragma unroll
        for (int mi = 0; mi < 4; ++mi)
            af[mi] = *(const bf16x8*)(As + (wm + mi * 16 + l16) * 32 + quad * 8);
#pragma unroll
        for (int ni = 0; ni < 4; ++ni)
            bfr[ni] = *(const bf16x8*)(Ws + (wn + ni * 16 + l16) * 32 + quad * 8);
#pragma unroll
        for (int mi = 0; mi < 4; ++mi)
#pragma unroll
            for (int ni = 0; ni < 4; ++ni)
                acc[mi][ni] = mfma_bf16(af[mi], bfr[ni], acc[mi][ni]);
    }

#pragma unroll
    for (int mi = 0; mi < 4; ++mi) {
        const int row0 = bm * 128 + wm + mi * 16 + quad * 4;
#pragma unroll
        for (int ni = 0; ni < 4; ++ni) {
            const int col = nb * 128 + wn + ni * 16 + l16;
            const float bvv = bsel[col];
            if (isK) {
#pragma unroll
                for (int r = 0; r < 4; ++r)
                    kout[(size_t)(row0 + r) * 1024 + col] = __float2bfloat16(acc[mi][ni][r] + bvv);
            } else {
                __align__(8) bf16 tmp[4];
#pragma unroll
                for (int r = 0; r < 4; ++r) tmp[r] = __float2bfloat16(acc[mi][ni][r] + bvv);
                const int b  = row0 >> 11;      // T = 2048
                const int t0 = row0 & 2047;
                bf16* dst = vt + ((size_t)(b * 1024 + col)) * 2048 + t0;
                *(short4*)dst = *(const short4*)tmp;
            }
        }
    }
}

// Flash attention, causal, balanced q-tile pairing. (v8, unchanged)
__global__ __launch_bounds__(256, 2) void attn_fwd(
    const bf16* __restrict__ qb, const bf16* __restrict__ kb,
    const bf16* __restrict__ vtb, bf16* __restrict__ ob)
{
    constexpr int T  = 2048;
    constexpr int DQ = 4096;
    constexpr int DK = 1024;

    __shared__ __align__(16) bf16 Ks[2][64 * 128];
    __shared__ __align__(16) bf16 Vs[2][128 * 64];
    __shared__ __align__(16) bf16 Ps[4][16][72];

    const int tid  = threadIdx.x;
    const int lane = tid & 63;
    const int wave = tid >> 6;
    const int quad = lane >> 4;
    const int l16  = lane & 15;
    const int swz  = l16 & 7;

    const int qi = blockIdx.x;    // 0..15
    const int bh = blockIdx.y;
    const int b  = bh >> 5;
    const int h  = bh & 31;
    const int g  = h >> 2;        // GROUP = 4
    const int qtB = 31 - qi;      // large tile
    const int qtA = qi;           // small tile
    const int q0B = qtB * 64;
    const int q0A = qtA * 64;
    const int qw = wave * 16;

    const bf16* Qg = qb  + (size_t)b * T * DQ + (size_t)h * 128;
    const bf16* Kg = kb  + (size_t)b * T * DK + (size_t)g * 128;
    const bf16* Vg = vtb + ((size_t)b * DK + g * 128) * T;
    bf16*       Og = ob  + (size_t)b * T * DQ + (size_t)h * 128;

    bf16x8 qf[2][4];
    {
        const size_t rB = (size_t)(q0B + qw + l16) * DQ;
        const size_t rA = (size_t)(q0A + qw + l16) * DQ;
#pragma unroll
        for (int kk = 0; kk < 4; ++kk) {
            qf[0][kk] = *(const bf16x8*)(Qg + rB + kk * 32 + quad * 8);
            qf[1][kk] = *(const bf16x8*)(Qg + rA + kk * 32 + quad * 8);
        }
    }

    const int krow_l = tid >> 4;
    const int kc16   = tid & 15;
    const int vrow_l = tid >> 3;
    const int vc16   = tid & 7;

    auto STAGE = [&](int st_, int bi_) {
        const int s0_ = st_ * 64;
        bf16* kbp = &Ks[bi_][0];
        bf16* vbp = &Vs[bi_][0];
#pragma unroll
        for (int i = 0; i < 4; ++i) {
            const int r = i * 16 + krow_l;
            async_copy16(kbp + (i * 256 + tid) * 8,
                         Kg + (size_t)(s0_ + r) * DK + ((kc16 ^ (r & 7)) * 8));
        }
#pragma unroll
        for (int i = 0; i < 4; ++i) {
            const int r = i * 32 + vrow_l;
            async_copy16(vbp + (i * 256 + tid) * 8,
                         Vg + (size_t)r * T + s0_ + ((vc16 ^ (r & 7)) * 8));
        }
    };

    floatx4 oacc[2][8];
#pragma unroll
    for (int t = 0; t < 2; ++t)
#pragma unroll
        for (int i = 0; i < 8; ++i) oacc[t][i] = (floatx4){0.f, 0.f, 0.f, 0.f};
    float m_run[2], l_run[2];
#pragma unroll
    for (int t = 0; t < 2; ++t) { m_run[t] = -1e30f; l_run[t] = 0.f; }

    const int bsrc = (lane & 48) + quad * 4;

    STAGE(0, 0);
    __syncthreads();

    for (int st = 0; st <= qtB; ++st) {
        const int bi = st & 1;
        const int s0 = st * 64;

        if (st < qtB) STAGE(st + 1, bi ^ 1);

        const bf16* Kb = &Ks[bi][0];
        const bf16* Vb = &Vs[bi][0];

        const int ntile = (st <= qtA) ? 2 : 1;
#pragma unroll
        for (int t = 0; t < 2; ++t) {
            if (t >= ntile) break;
            const int q0t  = t ? q0A : q0B;
            const int qt_t = t ? qtA : qtB;

            floatx4 sacc[4];
#pragma unroll
            for (int i = 0; i < 4; ++i) sacc[i] = (floatx4){0.f, 0.f, 0.f, 0.f};
#pragma unroll
            for (int kk = 0; kk < 4; ++kk) {
                const int koff = ((kk * 4 + quad) ^ swz) * 8;
                const bf16x8 qv = qf[t][kk];
#pragma unroll
                for (int ni = 0; ni < 4; ++ni) {
                    bf16x8 kf = *(const bf16x8*)(Kb + (ni * 16 + l16) * 128 + koff);
                    sacc[ni] = mfma_bf16(kf, qv, sacc[ni]);
                }
            }

            const bool diag = (st == qt_t);
            const int qg = q0t + qw + l16;
            float sv[4][4];
#pragma unroll
            for (int ni = 0; ni < 4; ++ni)
#pragma unroll
                for (int r = 0; r < 4; ++r) {
                    float x = sacc[ni][r];
                    if (diag && (s0 + ni * 16 + quad * 4 + r) > qg) x = -1e30f;
                    sv[ni][r] = x;
                }

            float pm[4];
#pragma unroll
            for (int ni = 0; ni < 4; ++ni)
                pm[ni] = fmaxf(fmaxf(sv[ni][0], sv[ni][1]), fmaxf(sv[ni][2], sv[ni][3]));
            float mx = fmaxf(fmaxf(pm[0], pm[1]), fmaxf(pm[2], pm[3]));
            mx = fmaxf(mx, __shfl_xor(mx, 16, 64));
            mx = fmaxf(mx, __shfl_xor(mx, 32, 64));

            const float mold  = m_run[t];
            const float mnew  = fmaxf(mold, mx);
            const float alpha = __expf(mold - mnew);
            m_run[t] = mnew;

            float ssum = 0.f;
#pragma unroll
            for (int ni = 0; ni < 4; ++ni) {
                __align__(8) bf16 pb[4];
#pragma unroll
                for (int r = 0; r < 4; ++r) {
                    float p = __expf(sv[ni][r] - mnew);
                    ssum += p;
                    pb[r] = __float2bfloat16(p);
                }
                *(short4*)&Ps[wave][l16][ni * 16 + quad * 4] = *(const short4*)pb;
            }
            ssum += __shfl_xor(ssum, 16, 64);
            ssum += __shfl_xor(ssum, 32, 64);
            l_run[t] = l_run[t] * alpha + ssum;

            float ar[4];
#pragma unroll
            for (int r = 0; r < 4; ++r) ar[r] = __shfl(alpha, bsrc + r, 64);
#pragma unroll
            for (int db = 0; db < 8; ++db)
#pragma unroll
                for (int r = 0; r < 4; ++r) oacc[t][db][r] *= ar[r];

            asm volatile("s_waitcnt lgkmcnt(0)" ::: "memory");

#pragma unroll
            for (int kk = 0; kk < 2; ++kk) {
                bf16x8 ap = *(const bf16x8*)&Ps[wave][l16][kk * 32 + quad * 8];
                const int voff = ((kk * 4 + quad) ^ swz) * 8;
#pragma unroll
                for (int db = 0; db < 8; ++db) {
                    bf16x8 bv8 = *(const bf16x8*)(Vb + (db * 16 + l16) * 64 + voff);
                    oacc[t][db] = mfma_bf16(ap, bv8, oacc[t][db]);
                }
            }
        }

        __syncthreads();
    }

#pragma unroll
    for (int t = 0; t < 2; ++t) {
        const int q0t = t ? q0A : q0B;
        const float linv = 1.0f / l_run[t];
        float ir[4];
#pragma unroll
        for (int r = 0; r < 4; ++r) ir[r] = __shfl(linv, bsrc + r, 64);
#pragma unroll
        for (int r = 0; r < 4; ++r) {
            const int qg = q0t + qw + quad * 4 + r;
#pragma unroll
            for (int db = 0; db < 8; ++db)
                Og[(size_t)qg * DQ + db * 16 + l16] = __float2bfloat16(oacc[t][db][r] * ir[r]);
        }
    }
}

extern "C" void kernel_launch(void* const* d_in, const int* in_sizes, int n_in,
                              void* d_out, int out_size, void* d_ws, size_t ws_size,
                              hipStream_t stream)
{
    const float* hs = (const float*)d_in[0];
    const float* Wq = (const float*)d_in[1];
    const float* bq = (const float*)d_in[2];
    const float* Wk = (const float*)d_in[3];
    const float* bk = (const float*)d_in[4];
    const float* Wv = (const float*)d_in[5];
    const float* bv = (const float*)d_in[6];
    const float* Wo = (const float*)d_in[7];
    const float* bo = (const float*)d_in[8];
    float* out = (float*)d_out;

    const int M  = 4096;         // B*T tokens
    const int D  = 4096;
    const int DK = 1024;         // G*d
    const size_t SZ_D  = (size_t)M * D;
    const size_t SZ_K  = (size_t)M * DK;

    bf16* hsb  = (bf16*)d_ws;            // [M][D]
    bf16* Wqb  = hsb  + SZ_D;            // [D][D]
    bf16* Wkb  = Wqb  + SZ_D;            // [DK][D]
    bf16* Wvb  = Wkb  + SZ_K;            // [DK][D]
    bf16* Wob  = Wvb  + SZ_K;            // [D][D]
    bf16* q_buf = Wob + SZ_D;            // [M][D]
    bf16* k_buf = q_buf + SZ_D;          // [M][DK]
    bf16* vt_buf = Wqb;                  // ALIAS: Wq consumed before KV-gemm writes vt
    bf16* o_buf  = hsb;                  // ALIAS: hs consumed before attn writes o

    const int CB = 256;
    cvt_f32_bf16<<<(int)(SZ_D / 4 + CB - 1) / CB, CB, 0, stream>>>(hs, hsb, (int)SZ_D);
    cvt_f32_bf16<<<(int)(SZ_D / 4 + CB - 1) / CB, CB, 0, stream>>>(Wq, Wqb, (int)SZ_D);
    cvt_f32_bf16<<<(int)(SZ_K / 4 + CB - 1) / CB, CB, 0, stream>>>(Wk, Wkb, (int)SZ_K);
    cvt_f32_bf16<<<(int)(SZ_K / 4 + CB - 1) / CB, CB, 0, stream>>>(Wv, Wvb, (int)SZ_K);
    cvt_f32_bf16<<<(int)(SZ_D / 4 + CB - 1) / CB, CB, 0, stream>>>(Wo, Wob, (int)SZ_D);

    const float scale = 0.08838834764831845f;  // 1/sqrt(128), folded into Q
    gemm256_bt_bias<0><<<dim3(M / 256, D / 256), dim3(512), 0, stream>>>(hsb, Wqb, bq, q_buf, M, D, D, scale);
    gemm_kv<<<dim3(M / 128, 16), dim3(256), 0, stream>>>(hsb, Wkb, Wvb, bk, bv, k_buf, vt_buf, M, D);
    attn_fwd<<<dim3(16, 64), dim3(256), 0, stream>>>(q_buf, k_buf, vt_buf, o_buf);
    gemm256_bt_bias<1><<<dim3(M / 256, D / 256), dim3(512), 0, stream>>>(o_buf, Wob, bo, out, M, D, D, 1.0f);
}